// Round 1
// baseline (325.441 us; speedup 1.0000x reference)
//
#include <hip/hip_runtime.h>

// MyAvgPool2D(56->56): stride=1, k=1 => identity. Pure copy of
// 32*512*56*56 = 51,380,224 fp32 (205.5 MB each direction).
//
// R0 lesson: hipMemcpyAsync D2D used the SDMA/blit path (~1.24 TB/s);
// compute-kernel float4 copy reaches ~6.3 TB/s (m13).
// R1 (this round): timed region = 2 harness poison-fills (248 us, fixed,
// already at 6.6 TB/s write ceiling) + our copy (~74 us @ 5.53 TB/s).
// Squeeze the copy toward 6.3 TB/s: 4x-unrolled strided copy (4 independent
// 16B loads in flight per thread before the dependent stores) + nontemporal
// load/store hints (zero-reuse stream, don't retain in L2). Grid is sized so
// 4 * gridDim * blockDim == n4 exactly (n4 = 12,845,056 = 1024 * 12,544)
// => no bounds check on the hot path.

typedef float f4 __attribute__((ext_vector_type(4)));

__global__ __launch_bounds__(256) void copy_f4x4_nt(
        const f4* __restrict__ src, f4* __restrict__ dst, int n4) {
    const int T = gridDim.x * blockDim.x;            // total threads
    int i = blockIdx.x * blockDim.x + threadIdx.x;   // coalesced: lane-contiguous
    const int i1 = i + T;
    const int i2 = i + 2 * T;
    const int i3 = i + 3 * T;
    if (i3 < n4) {
        // 4 independent loads issued back-to-back (vmcnt-pipelined), then 4 stores.
        f4 a = __builtin_nontemporal_load(src + i);
        f4 b = __builtin_nontemporal_load(src + i1);
        f4 c = __builtin_nontemporal_load(src + i2);
        f4 d = __builtin_nontemporal_load(src + i3);
        __builtin_nontemporal_store(a, dst + i);
        __builtin_nontemporal_store(b, dst + i1);
        __builtin_nontemporal_store(c, dst + i2);
        __builtin_nontemporal_store(d, dst + i3);
    } else {
        // Generic tail (unreachable for this shape; kept for safety).
        for (; i < n4; i += T) {
            __builtin_nontemporal_store(__builtin_nontemporal_load(src + i),
                                        dst + i);
        }
    }
}

extern "C" void kernel_launch(void* const* d_in, const int* in_sizes, int n_in,
                              void* d_out, int out_size, void* d_ws, size_t ws_size,
                              hipStream_t stream) {
    (void)n_in; (void)in_sizes; (void)d_ws; (void)ws_size;
    const f4* src = (const f4*)d_in[0];
    f4* dst = (f4*)d_out;
    const int n4 = out_size / 4;                 // 12,845,056 float4s
    const int block = 256;
    int grid = n4 / (block * 4);                 // 12,544 for this shape (exact)
    if (grid * block * 4 < n4) grid += 1;        // tail threads use the else-branch
    if (grid < 1) grid = 1;
    copy_f4x4_nt<<<grid, block, 0, stream>>>(src, dst, n4);
}